// Round 1
// baseline (894.703 us; speedup 1.0000x reference)
//
#include <hip/hip_runtime.h>
#include <math.h>

#define B_    16
#define C_    256
#define NPIX  4096      // H*W
#define K_    4
#define HID_  512
#define ITERS_ 3
#define NROWS (B_*NPIX) // 65536

__device__ __forceinline__ float gelu_f(float x) {
    return 0.5f * x * (1.0f + erff(x * 0.70710678118654752f));
}

// all-256-thread block reduce of two values (sum, sumsq)
__device__ __forceinline__ void block_reduce2(float v1, float v2, float* red1, float* red2,
                                              int tid, float& o1, float& o2) {
    red1[tid] = v1; red2[tid] = v2;
    __syncthreads();
    for (int s = 128; s > 0; s >>= 1) {
        if (tid < s) { red1[tid] += red1[tid + s]; red2[tid] += red2[tid + s]; }
        __syncthreads();
    }
    o1 = red1[0]; o2 = red2[0];
    __syncthreads();
}

// ---------------- W transpose: Wt[c][d] = (d<256 ? Wk[d][c] : Wv[d-256][c]) ----------------
__global__ void transpose_w_kernel(const float* __restrict__ Wk, const float* __restrict__ Wv,
                                   float* __restrict__ Wt) {
    int t = blockIdx.x * 256 + threadIdx.x;   // 0..131071
    int d = t >> 8;
    int c = t & 255;
    float v = (d < 256) ? Wk[d * 256 + c] : Wv[(d - 256) * 256 + c];
    Wt[(size_t)c * 512 + d] = v;
}

// ---------------- LN stats per (b,n) row over c ----------------
__global__ void ln_stats_kernel(const float* __restrict__ x, float* __restrict__ mean,
                                float* __restrict__ rstd) {
    int t = blockIdx.x * 256 + threadIdx.x;   // 0..65535
    int b = t >> 12;
    int n = t & 4095;
    const float* xb = x + (size_t)b * C_ * NPIX + n;
    float s = 0.f, s2 = 0.f;
    #pragma unroll 8
    for (int c = 0; c < C_; ++c) {
        float v = xb[(size_t)c * NPIX];
        s += v; s2 += v * v;
    }
    float m = s * (1.0f / C_);
    float var = s2 * (1.0f / C_) - m * m;
    mean[t] = m;
    rstd[t] = rsqrtf(var + 1e-5f);
}

// ---------------- slots init ----------------
__global__ void init_slots_kernel(const float* __restrict__ noise, const float* __restrict__ mu,
                                  const float* __restrict__ log_sigma, float* __restrict__ slots) {
    int t = blockIdx.x * 256 + threadIdx.x;   // 0..16383
    int c = t & 255;
    slots[t] = mu[c] + expf(log_sigma[c]) * noise[t];
}

// ---------------- fused LN + k/v projection GEMM ----------------
// A = xn (65536 x 256) built on the fly from x + LN; B = Wt (256 x 512, c-major)
// grid: (1024 row-tiles, 8 col-tiles), 256 threads, 64x64 tile, BK=32
__global__ __launch_bounds__(256) void kv_gemm_kernel(
    const float* __restrict__ x, const float* __restrict__ mean, const float* __restrict__ rstd,
    const float* __restrict__ g, const float* __restrict__ bta,
    const float* __restrict__ Wt,
    const float* __restrict__ bk, const float* __restrict__ bv,
    float* __restrict__ kbuf, float* __restrict__ vbuf) {
    __shared__ float as_[32][64];
    __shared__ float bs_[32][64];
    __shared__ float s_mean[64], s_rstd[64], s_g[C_], s_b[C_];

    const int tid = threadIdx.x;
    const int rt  = blockIdx.x;          // 0..1023
    const int b   = rt >> 6;
    const int n0  = (rt & 63) << 6;
    const int cy  = blockIdx.y;          // 0..7 -> global d0 = cy*64
    const bool is_k = (cy < 4);
    const float* bsel = is_k ? bk : bv;
    float* obuf = is_k ? kbuf : vbuf;
    const int dl0 = (cy & 3) << 6;       // local col base within 256

    if (tid < 64) {
        s_mean[tid] = mean[b * NPIX + n0 + tid];
        s_rstd[tid] = rstd[b * NPIX + n0 + tid];
    }
    s_g[tid] = g[tid];
    s_b[tid] = bta[tid];
    __syncthreads();

    float acc[4][4] = {};
    const int tm = tid >> 4, tn = tid & 15;

    for (int kc0 = 0; kc0 < C_; kc0 += 32) {
        // A tile: 64 m x 32 kc, LN fused
        #pragma unroll
        for (int p = 0; p < 8; ++p) {
            int kc = (tid >> 6) + (p << 2);
            int m  = tid & 63;
            int c  = kc0 + kc;
            float xv = x[((size_t)(b * C_ + c)) * NPIX + n0 + m];
            as_[kc][m] = (xv - s_mean[m]) * s_rstd[m] * s_g[c] + s_b[c];
        }
        // B tile from Wt (c-major): coalesced global + conflict-free LDS write
        #pragma unroll
        for (int p = 0; p < 8; ++p) {
            int nn = tid & 63;
            int kc = (tid >> 6) + (p << 2);
            bs_[kc][nn] = Wt[(size_t)(kc0 + kc) * 512 + (cy << 6) + nn];
        }
        __syncthreads();
        #pragma unroll
        for (int kc = 0; kc < 32; ++kc) {
            const float4 av = *reinterpret_cast<const float4*>(&as_[kc][tm << 2]);
            const float4 bw = *reinterpret_cast<const float4*>(&bs_[kc][tn << 2]);
            float a4[4] = {av.x, av.y, av.z, av.w};
            float b4[4] = {bw.x, bw.y, bw.z, bw.w};
            #pragma unroll
            for (int i = 0; i < 4; ++i)
                #pragma unroll
                for (int j = 0; j < 4; ++j)
                    acc[i][j] = fmaf(a4[i], b4[j], acc[i][j]);
        }
        __syncthreads();
    }

    const float4 bias4 = *reinterpret_cast<const float4*>(&bsel[dl0 + (tn << 2)]);
    #pragma unroll
    for (int i = 0; i < 4; ++i) {
        size_t r = (size_t)b * NPIX + n0 + (tm << 2) + i;
        float4 o;
        o.x = acc[i][0] + bias4.x;
        o.y = acc[i][1] + bias4.y;
        o.z = acc[i][2] + bias4.z;
        o.w = acc[i][3] + bias4.w;
        *reinterpret_cast<float4*>(&obuf[r * C_ + dl0 + (tn << 2)]) = o;
    }
}

// ---------------- slot LN + q projection (+ zero accumulators) ----------------
__global__ __launch_bounds__(256) void slot_q_kernel(
    const float* __restrict__ slots, const float* __restrict__ g_sl, const float* __restrict__ b_sl,
    const float* __restrict__ Wq, const float* __restrict__ bq,
    float* __restrict__ qbuf, float* __restrict__ upd, float* __restrict__ asum) {
    __shared__ float snorm[256];
    __shared__ float red1[256], red2[256];
    int tid = threadIdx.x;
    int r = blockIdx.x;                 // b*K + k
    float v = slots[r * C_ + tid];
    float sm, s2;
    block_reduce2(v, v * v, red1, red2, tid, sm, s2);
    float m = sm * (1.f / C_);
    float rs = rsqrtf(s2 * (1.f / C_) - m * m + 1e-5f);
    snorm[tid] = (v - m) * rs * g_sl[tid] + b_sl[tid];
    __syncthreads();
    float qv = bq[tid];
    const float* wr = Wq + (size_t)tid * C_;
    #pragma unroll 8
    for (int c = 0; c < C_; ++c) qv += wr[c] * snorm[c];
    qbuf[r * C_ + tid] = qv;
    upd[r * C_ + tid] = 0.f;
    if (tid == 0) asum[r] = 0.f;
}

// ---------------- attention: logits, softmax over K, partial weighted-v sums ----------------
// grid (16 n-tiles, 16 batches), 256 threads; each block handles 256 n positions
__global__ __launch_bounds__(256) void attn_kernel(
    const float* __restrict__ qbuf, const float* __restrict__ kbuf, const float* __restrict__ vbuf,
    float* __restrict__ upd, float* __restrict__ asum) {
    __shared__ float qs[K_ * C_];       // 1024
    __shared__ float tile[64][65];
    __shared__ float lsm[K_ * 64];
    __shared__ float attnw[K_ * 64];

    int tid = threadIdx.x;
    int b = blockIdx.y;
    int n_blk = blockIdx.x << 8;        // *256

    #pragma unroll
    for (int i = 0; i < 4; ++i) qs[tid + i * 256] = qbuf[b * (K_ * C_) + tid + i * 256];

    const int kk = tid >> 6;            // slot index 0..3
    const int cl = tid & 63;
    float accU[4] = {0.f, 0.f, 0.f, 0.f};
    float asum_loc = 0.f;
    __syncthreads();

    for (int st = 0; st < 4; ++st) {
        int n0 = n_blk + (st << 6);
        const float* krows = kbuf + ((size_t)b * NPIX + n0) * C_;
        float lacc = 0.f;
        for (int ci = 0; ci < 4; ++ci) {
            #pragma unroll
            for (int p = 0; p < 16; ++p) {
                int nn = (tid >> 6) + (p << 2);
                tile[nn][cl] = krows[(size_t)nn * C_ + (ci << 6) + cl];
            }
            __syncthreads();
            const float* qrow = qs + kk * C_ + (ci << 6);
            #pragma unroll
            for (int cc = 0; cc < 64; ++cc)
                lacc = fmaf(qrow[cc], tile[cl][cc], lacc);
            __syncthreads();
        }
        lsm[kk * 64 + cl] = lacc * 0.0625f;   // scale = C^-0.5 = 1/16
        __syncthreads();
        if (tid < 64) {
            float l0 = lsm[tid], l1 = lsm[64 + tid], l2 = lsm[128 + tid], l3 = lsm[192 + tid];
            float mx = fmaxf(fmaxf(l0, l1), fmaxf(l2, l3));
            float e0 = expf(l0 - mx), e1 = expf(l1 - mx), e2 = expf(l2 - mx), e3 = expf(l3 - mx);
            float inv = 1.0f / (e0 + e1 + e2 + e3);
            attnw[tid] = e0 * inv; attnw[64 + tid] = e1 * inv;
            attnw[128 + tid] = e2 * inv; attnw[192 + tid] = e3 * inv;
        }
        __syncthreads();
        if (tid < 4) {
            float s = 0.f;
            #pragma unroll 8
            for (int nn = 0; nn < 64; ++nn) s += attnw[tid * 64 + nn];
            asum_loc += s;
        }
        const float* vrows = vbuf + ((size_t)b * NPIX + n0) * C_;
        for (int ci = 0; ci < 4; ++ci) {
            #pragma unroll
            for (int p = 0; p < 16; ++p) {
                int nn = (tid >> 6) + (p << 2);
                tile[nn][cl] = vrows[(size_t)nn * C_ + (ci << 6) + cl];
            }
            __syncthreads();
            const float* aw = attnw + kk * 64;
            float a = accU[ci];
            #pragma unroll
            for (int nn = 0; nn < 64; ++nn)
                a = fmaf(aw[nn], tile[nn][cl], a);
            accU[ci] = a;
            __syncthreads();
        }
    }
    #pragma unroll
    for (int ci = 0; ci < 4; ++ci)
        atomicAdd(&upd[((size_t)b * K_ + kk) * C_ + (ci << 6) + cl], accU[ci]);
    if (tid < 4) atomicAdd(&asum[b * K_ + tid], asum_loc);
}

// ---------------- slot update: Wu GEMM + residual + LN + MLP ----------------
__global__ __launch_bounds__(256) void slot_update_kernel(
    float* __restrict__ slots, const float* __restrict__ upd, const float* __restrict__ asum,
    const float* __restrict__ Wu, const float* __restrict__ bu,
    const float* __restrict__ g_mlp, const float* __restrict__ b_mlp,
    const float* __restrict__ W1, const float* __restrict__ b1,
    const float* __restrict__ W2, const float* __restrict__ b2) {
    __shared__ float comb[512];
    __shared__ float mrow[256];
    __shared__ float hrow[512];
    __shared__ float red1[256], red2[256];
    int tid = threadIdx.x;
    int r = blockIdx.x;
    float prev = slots[r * C_ + tid];
    comb[tid] = prev;
    float denom = asum[r] + 1e-8f;
    comb[256 + tid] = upd[r * C_ + tid] / denom;
    __syncthreads();
    float nv = bu[tid] + prev;
    const float* wrow = Wu + (size_t)tid * 512;
    #pragma unroll 8
    for (int c = 0; c < 512; ++c) nv = fmaf(wrow[c], comb[c], nv);
    float sm, s2;
    block_reduce2(nv, nv * nv, red1, red2, tid, sm, s2);
    float m = sm * (1.f / C_);
    float rs = rsqrtf(s2 * (1.f / C_) - m * m + 1e-5f);
    mrow[tid] = (nv - m) * rs * g_mlp[tid] + b_mlp[tid];
    __syncthreads();
    #pragma unroll
    for (int rep = 0; rep < 2; ++rep) {
        int j = tid + rep * 256;
        float hv = b1[j];
        const float* w1r = W1 + (size_t)j * C_;
        #pragma unroll 8
        for (int c = 0; c < C_; ++c) hv = fmaf(w1r[c], mrow[c], hv);
        hrow[j] = gelu_f(hv);
    }
    __syncthreads();
    float ov = nv + b2[tid];
    const float* w2r = W2 + (size_t)tid * 512;
    #pragma unroll 8
    for (int c = 0; c < 512; ++c) ov = fmaf(w2r[c], hrow[c], ov);
    slots[r * C_ + tid] = ov;
}

// ---------------- final head: copy slots, e = gelu(slots@We1^T+be1), sw = sigmoid(e@We2+be2) ----
__global__ __launch_bounds__(256) void final_kernel(
    const float* __restrict__ slots, const float* __restrict__ We1, const float* __restrict__ be1,
    const float* __restrict__ We2, const float* __restrict__ be2, float* __restrict__ out) {
    __shared__ float srow[256];
    __shared__ float erow[128];
    int tid = threadIdx.x;
    int r = blockIdx.x;
    float sv = slots[r * C_ + tid];
    srow[tid] = sv;
    out[r * C_ + tid] = sv;
    __syncthreads();
    if (tid < 128) {
        float ev = be1[tid];
        const float* wr = We1 + (size_t)tid * C_;
        #pragma unroll 8
        for (int c = 0; c < C_; ++c) ev = fmaf(wr[c], srow[c], ev);
        erow[tid] = gelu_f(ev);
    }
    __syncthreads();
    if (tid == 0) {
        float acc = be2[0];
        #pragma unroll 8
        for (int j = 0; j < 128; ++j) acc = fmaf(We2[j], erow[j], acc);
        out[B_ * K_ * C_ + r] = 1.0f / (1.0f + expf(-acc));
    }
}

extern "C" void kernel_launch(void* const* d_in, const int* in_sizes, int n_in,
                              void* d_out, int out_size, void* d_ws, size_t ws_size,
                              hipStream_t stream) {
    (void)in_sizes; (void)n_in; (void)out_size; (void)ws_size;
    const float* x        = (const float*)d_in[0];
    const float* noise    = (const float*)d_in[1];
    const float* slot_mu  = (const float*)d_in[2];
    const float* slot_ls  = (const float*)d_in[3];
    const float* ln_in_g  = (const float*)d_in[4];
    const float* ln_in_b  = (const float*)d_in[5];
    const float* ln_sl_g  = (const float*)d_in[6];
    const float* ln_sl_b  = (const float*)d_in[7];
    const float* ln_mlp_g = (const float*)d_in[8];
    const float* ln_mlp_b = (const float*)d_in[9];
    const float* Wq = (const float*)d_in[10];
    const float* bq = (const float*)d_in[11];
    const float* Wk = (const float*)d_in[12];
    const float* bk = (const float*)d_in[13];
    const float* Wv = (const float*)d_in[14];
    const float* bv = (const float*)d_in[15];
    const float* Wu = (const float*)d_in[16];
    const float* bu = (const float*)d_in[17];
    const float* W1 = (const float*)d_in[18];
    const float* b1 = (const float*)d_in[19];
    const float* W2 = (const float*)d_in[20];
    const float* b2 = (const float*)d_in[21];
    const float* We1 = (const float*)d_in[22];
    const float* be1 = (const float*)d_in[23];
    const float* We2 = (const float*)d_in[24];
    const float* be2 = (const float*)d_in[25];
    float* out = (float*)d_out;

    float* ws = (float*)d_ws;
    float* kbuf  = ws;                       // 16777216
    float* vbuf  = kbuf + (size_t)NROWS * C_;     // 16777216
    float* meanb = vbuf + (size_t)NROWS * C_;     // 65536
    float* rstdb = meanb + NROWS;            // 65536
    float* slots = rstdb + NROWS;            // 16384
    float* qbuf  = slots + B_ * K_ * C_;     // 16384
    float* updb  = qbuf + B_ * K_ * C_;      // 16384
    float* asumb = updb + B_ * K_ * C_;      // 64
    float* Wt    = asumb + B_ * K_;          // 131072

    transpose_w_kernel<<<512, 256, 0, stream>>>(Wk, Wv, Wt);
    ln_stats_kernel<<<NROWS / 256, 256, 0, stream>>>(x, meanb, rstdb);
    init_slots_kernel<<<B_ * K_, 256, 0, stream>>>(noise, slot_mu, slot_ls, slots);
    kv_gemm_kernel<<<dim3(1024, 8), 256, 0, stream>>>(x, meanb, rstdb, ln_in_g, ln_in_b,
                                                      Wt, bk, bv, kbuf, vbuf);
    for (int it = 0; it < ITERS_; ++it) {
        slot_q_kernel<<<B_ * K_, 256, 0, stream>>>(slots, ln_sl_g, ln_sl_b, Wq, bq,
                                                   qbuf, updb, asumb);
        attn_kernel<<<dim3(16, 16), 256, 0, stream>>>(qbuf, kbuf, vbuf, updb, asumb);
        slot_update_kernel<<<B_ * K_, 256, 0, stream>>>(slots, updb, asumb, Wu, bu,
                                                        ln_mlp_g, ln_mlp_b, W1, b1, W2, b2);
    }
    final_kernel<<<B_ * K_, 256, 0, stream>>>(slots, We1, be1, We2, be2, out);
}

// Round 2
// 728.722 us; speedup vs baseline: 1.2278x; 1.2278x over previous
//
#include <hip/hip_runtime.h>
#include <math.h>

#define B_    16
#define C_    256
#define NPIX  4096      // H*W
#define K_    4
#define HID_  512
#define ITERS_ 3
#define NROWS (B_*NPIX) // 65536

typedef __attribute__((ext_vector_type(8))) short bf16x8;
typedef __attribute__((ext_vector_type(4))) float f32x4;

__device__ __forceinline__ float gelu_f(float x) {
    return 0.5f * x * (1.0f + erff(x * 0.70710678118654752f));
}

__device__ __forceinline__ unsigned short f2bf(float x) {
    union { float f; unsigned u; } v; v.f = x;
    unsigned r = v.u + 0x7fffu + ((v.u >> 16) & 1u);   // round-nearest-even
    return (unsigned short)(r >> 16);
}
__device__ __forceinline__ float bf2f(unsigned short u) {
    union { unsigned u; float f; } v; v.u = ((unsigned)u) << 16;
    return v.f;
}

// async global->LDS, 16B per lane; LDS dest = wave-uniform base + lane*16
__device__ __forceinline__ void async_load16(const void* g, void* l) {
    __builtin_amdgcn_global_load_lds(
        (const __attribute__((address_space(1))) unsigned int*)g,
        (__attribute__((address_space(3))) unsigned int*)l, 16, 0, 0);
}

// all-256-thread block reduce of two values (sum, sumsq)
__device__ __forceinline__ void block_reduce2(float v1, float v2, float* red1, float* red2,
                                              int tid, float& o1, float& o2) {
    red1[tid] = v1; red2[tid] = v2;
    __syncthreads();
    for (int s = 128; s > 0; s >>= 1) {
        if (tid < s) { red1[tid] += red1[tid + s]; red2[tid] += red2[tid + s]; }
        __syncthreads();
    }
    o1 = red1[0]; o2 = red2[0];
    __syncthreads();
}

// ---------------- weight convert: Wtb[d][c] = bf16( (d<256?Wk:Wv)[d%256][c] ) ----------------
__global__ void wtb_kernel(const float* __restrict__ Wk, const float* __restrict__ Wv,
                           unsigned short* __restrict__ Wtb) {
    int t = blockIdx.x * 256 + threadIdx.x;   // 0..131071
    int d = t >> 8;
    int c = t & 255;
    float v = (d < 256) ? Wk[d * 256 + c] : Wv[(d - 256) * 256 + c];
    Wtb[t] = f2bf(v);
}

// ---------------- LN stats per (b,n) row over c ----------------
__global__ void ln_stats_kernel(const float* __restrict__ x, float* __restrict__ mean,
                                float* __restrict__ rstd) {
    int t = blockIdx.x * 256 + threadIdx.x;   // 0..65535
    int b = t >> 12;
    int n = t & 4095;
    const float* xb = x + (size_t)b * C_ * NPIX + n;
    float s = 0.f, s2 = 0.f;
    #pragma unroll 8
    for (int c = 0; c < C_; ++c) {
        float v = xb[(size_t)c * NPIX];
        s += v; s2 += v * v;
    }
    float m = s * (1.0f / C_);
    float var = s2 * (1.0f / C_) - m * m;
    mean[t] = m;
    rstd[t] = rsqrtf(var + 1e-5f);
}

// ---------------- slots init ----------------
__global__ void init_slots_kernel(const float* __restrict__ noise, const float* __restrict__ mu,
                                  const float* __restrict__ log_sigma, float* __restrict__ slots) {
    int t = blockIdx.x * 256 + threadIdx.x;   // 0..16383
    int c = t & 255;
    slots[t] = mu[c] + expf(log_sigma[c]) * noise[t];
}

// ---------------- LN + transpose + bf16 convert: xnb[b*4096+n][c] ----------------
// grid (64 n-tiles, 4 c-tiles, 16 b), 256 threads; 64n x 64c tile per block
__global__ __launch_bounds__(256) void xn_bf16_kernel(
    const float* __restrict__ x, const float* __restrict__ mean, const float* __restrict__ rstd,
    const float* __restrict__ g, const float* __restrict__ bta,
    unsigned short* __restrict__ xnb) {
    __shared__ float tile[64][65];
    int tid = threadIdx.x;
    int nt = blockIdx.x << 6, ct = blockIdx.y << 6, b = blockIdx.z;
    // load coalesced over n
    #pragma unroll
    for (int r = 0; r < 16; ++r) {
        int idx = tid + (r << 8);
        int c_l = idx >> 6, n_l = idx & 63;
        tile[c_l][n_l] = x[(size_t)(b * C_ + ct + c_l) * NPIX + nt + n_l];
    }
    __syncthreads();
    // write rows (c contiguous) as ushort2
    #pragma unroll
    for (int r = 0; r < 8; ++r) {
        int idx = tid + (r << 8);         // 0..2047
        int n_l = idx >> 5, cp = idx & 31;
        int c0 = cp << 1;
        int gn = b * NPIX + nt + n_l;
        float mn = mean[gn], rs = rstd[gn];
        float v0 = (tile[c0][n_l] - mn) * rs * g[ct + c0] + bta[ct + c0];
        float v1 = (tile[c0 + 1][n_l] - mn) * rs * g[ct + c0 + 1] + bta[ct + c0 + 1];
        ushort2 o; o.x = f2bf(v0); o.y = f2bf(v1);
        *reinterpret_cast<ushort2*>(&xnb[(size_t)gn * C_ + ct + c0]) = o;
    }
}

// ---------------- bf16 MFMA k/v projection GEMM ----------------
// C[m][d] = sum_c xnb[m][c]*Wtb[d][c] (+bias); 128x128 tile, BK=32, m97 structure
// grid (512 m-tiles, 4 d-tiles), 256 threads = 4 waves, each wave 64x64
__global__ __launch_bounds__(256) void kv_gemm_mfma(
    const unsigned short* __restrict__ xnb, const unsigned short* __restrict__ Wtb,
    const float* __restrict__ bk, const float* __restrict__ bv,
    unsigned short* __restrict__ kbuf, unsigned short* __restrict__ vbuf) {
    __shared__ __align__(16) short As[128 * 32];
    __shared__ __align__(16) short Bs[128 * 32];
    const int tid = threadIdx.x;
    const int wave = tid >> 6, lane = tid & 63;
    const int mtile = blockIdx.x << 7;
    const int ntile = blockIdx.y << 7;
    const int wr = wave >> 1, wc = wave & 1;

    f32x4 acc[4][4];
    #pragma unroll
    for (int i = 0; i < 4; ++i)
        #pragma unroll
        for (int j = 0; j < 4; ++j) acc[i][j] = (f32x4)0.f;

    const int lrow = lane >> 2;          // 0..15
    const int lk   = (lane & 3) << 3;    // 0,8,16,24 (ushort)

    for (int kc0 = 0; kc0 < C_; kc0 += 32) {
        // stage A,B: wave w covers rows [w*32, w*32+32), 2 lds-instrs each
        #pragma unroll
        for (int j = 0; j < 2; ++j) {
            int row = (wave << 5) + (j << 4) + lrow;
            async_load16(&xnb[(size_t)(mtile + row) * C_ + kc0 + lk],
                         &As[(wave << 10) + (j << 9)]);
            async_load16(&Wtb[(size_t)(ntile + row) * C_ + kc0 + lk],
                         &Bs[(wave << 10) + (j << 9)]);
        }
        __syncthreads();
        bf16x8 af[4], bfr[4];
        #pragma unroll
        for (int mi = 0; mi < 4; ++mi)
            af[mi] = *reinterpret_cast<const bf16x8*>(
                &As[((wr << 6) + (mi << 4) + (lane & 15)) * 32 + ((lane >> 4) << 3)]);
        #pragma unroll
        for (int ni = 0; ni < 4; ++ni)
            bfr[ni] = *reinterpret_cast<const bf16x8*>(
                &Bs[((wc << 6) + (ni << 4) + (lane & 15)) * 32 + ((lane >> 4) << 3)]);
        #pragma unroll
        for (int mi = 0; mi < 4; ++mi)
            #pragma unroll
            for (int ni = 0; ni < 4; ++ni)
                acc[mi][ni] = __builtin_amdgcn_mfma_f32_16x16x32_bf16(
                    af[mi], bfr[ni], acc[mi][ni], 0, 0, 0);
        __syncthreads();
    }

    // epilogue: D row=(lane>>4)*4+reg, col=lane&15
    #pragma unroll
    for (int ni = 0; ni < 4; ++ni) {
        int col = ntile + (wc << 6) + (ni << 4) + (lane & 15);
        bool is_k = (col < 256);
        float bias = is_k ? bk[col] : bv[col - 256];
        unsigned short* obuf = is_k ? kbuf : vbuf;
        int cl = is_k ? col : (col - 256);
        #pragma unroll
        for (int mi = 0; mi < 4; ++mi) {
            int row0 = mtile + (wr << 6) + (mi << 4) + ((lane >> 4) << 2);
            #pragma unroll
            for (int r = 0; r < 4; ++r)
                obuf[(size_t)(row0 + r) * C_ + cl] = f2bf(acc[mi][ni][r] + bias);
        }
    }
}

// ---------------- slot LN + q projection (+ zero accumulators) ----------------
__global__ __launch_bounds__(256) void slot_q_kernel(
    const float* __restrict__ slots, const float* __restrict__ g_sl, const float* __restrict__ b_sl,
    const float* __restrict__ Wq, const float* __restrict__ bq,
    float* __restrict__ qbuf, float* __restrict__ upd, float* __restrict__ asum) {
    __shared__ float snorm[256];
    __shared__ float red1[256], red2[256];
    int tid = threadIdx.x;
    int r = blockIdx.x;                 // b*K + k
    float v = slots[r * C_ + tid];
    float sm, s2;
    block_reduce2(v, v * v, red1, red2, tid, sm, s2);
    float m = sm * (1.f / C_);
    float rs = rsqrtf(s2 * (1.f / C_) - m * m + 1e-5f);
    snorm[tid] = (v - m) * rs * g_sl[tid] + b_sl[tid];
    __syncthreads();
    float qv = bq[tid];
    const float* wr = Wq + (size_t)tid * C_;
    #pragma unroll 8
    for (int c = 0; c < C_; ++c) qv += wr[c] * snorm[c];
    qbuf[r * C_ + tid] = qv;
    upd[r * C_ + tid] = 0.f;
    if (tid == 0) asum[r] = 0.f;
}

// ---------------- attention: logits, softmax over K, partial weighted-v sums ----------------
// grid (16 n-tiles, 16 batches), 256 threads; each block handles 256 n positions
__global__ __launch_bounds__(256) void attn_kernel(
    const float* __restrict__ qbuf, const unsigned short* __restrict__ kbuf,
    const unsigned short* __restrict__ vbuf,
    float* __restrict__ upd, float* __restrict__ asum) {
    __shared__ float qs[K_ * C_];       // 1024
    __shared__ float tile[64][65];
    __shared__ float lsm[K_ * 64];
    __shared__ float attnw[K_ * 64];

    int tid = threadIdx.x;
    int b = blockIdx.y;
    int n_blk = blockIdx.x << 8;        // *256

    #pragma unroll
    for (int i = 0; i < 4; ++i) qs[tid + i * 256] = qbuf[b * (K_ * C_) + tid + i * 256];

    const int kk = tid >> 6;            // slot index 0..3
    const int cl = tid & 63;
    float accU[4] = {0.f, 0.f, 0.f, 0.f};
    float asum_loc = 0.f;
    __syncthreads();

    for (int st = 0; st < 4; ++st) {
        int n0 = n_blk + (st << 6);
        const unsigned short* krows = kbuf + ((size_t)b * NPIX + n0) * C_;
        float lacc = 0.f;
        for (int ci = 0; ci < 4; ++ci) {
            #pragma unroll
            for (int p = 0; p < 16; ++p) {
                int nn = (tid >> 6) + (p << 2);
                tile[nn][cl] = bf2f(krows[(size_t)nn * C_ + (ci << 6) + cl]);
            }
            __syncthreads();
            const float* qrow = qs + kk * C_ + (ci << 6);
            #pragma unroll
            for (int cc = 0; cc < 64; ++cc)
                lacc = fmaf(qrow[cc], tile[cl][cc], lacc);
            __syncthreads();
        }
        lsm[kk * 64 + cl] = lacc * 0.0625f;   // scale = C^-0.5 = 1/16
        __syncthreads();
        if (tid < 64) {
            float l0 = lsm[tid], l1 = lsm[64 + tid], l2 = lsm[128 + tid], l3 = lsm[192 + tid];
            float mx = fmaxf(fmaxf(l0, l1), fmaxf(l2, l3));
            float e0 = expf(l0 - mx), e1 = expf(l1 - mx), e2 = expf(l2 - mx), e3 = expf(l3 - mx);
            float inv = 1.0f / (e0 + e1 + e2 + e3);
            attnw[tid] = e0 * inv; attnw[64 + tid] = e1 * inv;
            attnw[128 + tid] = e2 * inv; attnw[192 + tid] = e3 * inv;
        }
        __syncthreads();
        if (tid < 4) {
            float s = 0.f;
            #pragma unroll 8
            for (int nn = 0; nn < 64; ++nn) s += attnw[tid * 64 + nn];
            asum_loc += s;
        }
        const unsigned short* vrows = vbuf + ((size_t)b * NPIX + n0) * C_;
        for (int ci = 0; ci < 4; ++ci) {
            #pragma unroll
            for (int p = 0; p < 16; ++p) {
                int nn = (tid >> 6) + (p << 2);
                tile[nn][cl] = bf2f(vrows[(size_t)nn * C_ + (ci << 6) + cl]);
            }
            __syncthreads();
            const float* aw = attnw + kk * 64;
            float a = accU[ci];
            #pragma unroll
            for (int nn = 0; nn < 64; ++nn)
                a = fmaf(aw[nn], tile[nn][cl], a);
            accU[ci] = a;
            __syncthreads();
        }
    }
    #pragma unroll
    for (int ci = 0; ci < 4; ++ci)
        atomicAdd(&upd[((size_t)b * K_ + kk) * C_ + (ci << 6) + cl], accU[ci]);
    if (tid < 4) atomicAdd(&asum[b * K_ + tid], asum_loc);
}

// ---------------- slot update: Wu GEMM + residual + LN + MLP ----------------
__global__ __launch_bounds__(256) void slot_update_kernel(
    float* __restrict__ slots, const float* __restrict__ upd, const float* __restrict__ asum,
    const float* __restrict__ Wu, const float* __restrict__ bu,
    const float* __restrict__ g_mlp, const float* __restrict__ b_mlp,
    const float* __restrict__ W1, const float* __restrict__ b1,
    const float* __restrict__ W2, const float* __restrict__ b2) {
    __shared__ float comb[512];
    __shared__ float mrow[256];
    __shared__ float hrow[512];
    __shared__ float red1[256], red2[256];
    int tid = threadIdx.x;
    int r = blockIdx.x;
    float prev = slots[r * C_ + tid];
    comb[tid] = prev;
    float denom = asum[r] + 1e-8f;
    comb[256 + tid] = upd[r * C_ + tid] / denom;
    __syncthreads();
    float nv = bu[tid] + prev;
    const float* wrow = Wu + (size_t)tid * 512;
    #pragma unroll 8
    for (int c = 0; c < 512; ++c) nv = fmaf(wrow[c], comb[c], nv);
    float sm, s2;
    block_reduce2(nv, nv * nv, red1, red2, tid, sm, s2);
    float m = sm * (1.f / C_);
    float rs = rsqrtf(s2 * (1.f / C_) - m * m + 1e-5f);
    mrow[tid] = (nv - m) * rs * g_mlp[tid] + b_mlp[tid];
    __syncthreads();
    #pragma unroll
    for (int rep = 0; rep < 2; ++rep) {
        int j = tid + rep * 256;
        float hv = b1[j];
        const float* w1r = W1 + (size_t)j * C_;
        #pragma unroll 8
        for (int c = 0; c < C_; ++c) hv = fmaf(w1r[c], mrow[c], hv);
        hrow[j] = gelu_f(hv);
    }
    __syncthreads();
    float ov = nv + b2[tid];
    const float* w2r = W2 + (size_t)tid * 512;
    #pragma unroll 8
    for (int c = 0; c < 512; ++c) ov = fmaf(w2r[c], hrow[c], ov);
    slots[r * C_ + tid] = ov;
}

// ---------------- final head ----------------
__global__ __launch_bounds__(256) void final_kernel(
    const float* __restrict__ slots, const float* __restrict__ We1, const float* __restrict__ be1,
    const float* __restrict__ We2, const float* __restrict__ be2, float* __restrict__ out) {
    __shared__ float srow[256];
    __shared__ float erow[128];
    int tid = threadIdx.x;
    int r = blockIdx.x;
    float sv = slots[r * C_ + tid];
    srow[tid] = sv;
    out[r * C_ + tid] = sv;
    __syncthreads();
    if (tid < 128) {
        float ev = be1[tid];
        const float* wr = We1 + (size_t)tid * C_;
        #pragma unroll 8
        for (int c = 0; c < C_; ++c) ev = fmaf(wr[c], srow[c], ev);
        erow[tid] = gelu_f(ev);
    }
    __syncthreads();
    if (tid == 0) {
        float acc = be2[0];
        #pragma unroll 8
        for (int j = 0; j < 128; ++j) acc = fmaf(We2[j], erow[j], acc);
        out[B_ * K_ * C_ + r] = 1.0f / (1.0f + expf(-acc));
    }
}

extern "C" void kernel_launch(void* const* d_in, const int* in_sizes, int n_in,
                              void* d_out, int out_size, void* d_ws, size_t ws_size,
                              hipStream_t stream) {
    (void)in_sizes; (void)n_in; (void)out_size; (void)ws_size;
    const float* x        = (const float*)d_in[0];
    const float* noise    = (const float*)d_in[1];
    const float* slot_mu  = (const float*)d_in[2];
    const float* slot_ls  = (const float*)d_in[3];
    const float* ln_in_g  = (const float*)d_in[4];
    const float* ln_in_b  = (const float*)d_in[5];
    const float* ln_sl_g  = (const float*)d_in[6];
    const float* ln_sl_b  = (const float*)d_in[7];
    const float* ln_mlp_g = (const float*)d_in[8];
    const float* ln_mlp_b = (const float*)d_in[9];
    const float* Wq = (const float*)d_in[10];
    const float* bq = (const float*)d_in[11];
    const float* Wk = (const float*)d_in[12];
    const float* bk = (const float*)d_in[13];
    const float* Wv = (const float*)d_in[14];
    const float* bv = (const float*)d_in[15];
    const float* Wu = (const float*)d_in[16];
    const float* bu = (const float*)d_in[17];
    const float* W1 = (const float*)d_in[18];
    const float* b1 = (const float*)d_in[19];
    const float* W2 = (const float*)d_in[20];
    const float* b2 = (const float*)d_in[21];
    const float* We1 = (const float*)d_in[22];
    const float* be1 = (const float*)d_in[23];
    const float* We2 = (const float*)d_in[24];
    const float* be2 = (const float*)d_in[25];
    float* out = (float*)d_out;

    char* ws = (char*)d_ws;
    unsigned short* kbuf = (unsigned short*)ws;                 // 32 MiB
    unsigned short* vbuf = kbuf + (size_t)NROWS * C_;           // 32 MiB
    unsigned short* xnb  = vbuf + (size_t)NROWS * C_;           // 32 MiB
    unsigned short* Wtb  = xnb + (size_t)NROWS * C_;            // 256 KiB
    float* meanb = (float*)(Wtb + 512 * C_);
    float* rstdb = meanb + NROWS;
    float* slots = rstdb + NROWS;
    float* qbuf  = slots + B_ * K_ * C_;
    float* updb  = qbuf + B_ * K_ * C_;
    float* asumb = updb + B_ * K_ * C_;

    wtb_kernel<<<512, 256, 0, stream>>>(Wk, Wv, Wtb);
    ln_stats_kernel<<<NROWS / 256, 256, 0, stream>>>(x, meanb, rstdb);
    init_slots_kernel<<<B_ * K_, 256, 0, stream>>>(noise, slot_mu, slot_ls, slots);
    xn_bf16_kernel<<<dim3(64, 4, 16), 256, 0, stream>>>(x, meanb, rstdb, ln_in_g, ln_in_b, xnb);
    kv_gemm_mfma<<<dim3(512, 4), 256, 0, stream>>>(xnb, Wtb, bk, bv, kbuf, vbuf);
    for (int it = 0; it < ITERS_; ++it) {
        slot_q_kernel<<<B_ * K_, 256, 0, stream>>>(slots, ln_sl_g, ln_sl_b, Wq, bq,
                                                   qbuf, updb, asumb);
        attn_kernel<<<dim3(16, 16), 256, 0, stream>>>(qbuf, kbuf, vbuf, updb, asumb);
        slot_update_kernel<<<B_ * K_, 256, 0, stream>>>(slots, updb, asumb, Wu, bu,
                                                        ln_mlp_g, ln_mlp_b, W1, b1, W2, b2);
    }
    final_kernel<<<B_ * K_, 256, 0, stream>>>(slots, We1, be1, We2, be2, out);
}

// Round 3
// 487.443 us; speedup vs baseline: 1.8355x; 1.4950x over previous
//
#include <hip/hip_runtime.h>
#include <math.h>

#define B_    16
#define C_    256
#define NPIX  4096      // H*W
#define K_    4
#define HID_  512
#define ITERS_ 3
#define NROWS (B_*NPIX) // 65536

typedef __attribute__((ext_vector_type(8))) short bf16x8;
typedef __attribute__((ext_vector_type(4))) float f32x4;
typedef unsigned short ushort_t;

__device__ __forceinline__ float gelu_f(float x) {
    return 0.5f * x * (1.0f + erff(x * 0.70710678118654752f));
}

__device__ __forceinline__ unsigned short f2bf(float x) {
    union { float f; unsigned u; } v; v.f = x;
    unsigned r = v.u + 0x7fffu + ((v.u >> 16) & 1u);   // round-nearest-even
    return (unsigned short)(r >> 16);
}
__device__ __forceinline__ float bf2f(unsigned short u) {
    union { unsigned u; float f; } v; v.u = ((unsigned)u) << 16;
    return v.f;
}
__device__ __forceinline__ float bflo(unsigned u) {
    union { unsigned u; float f; } v; v.u = u << 16; return v.f;
}
__device__ __forceinline__ float bfhi(unsigned u) {
    union { unsigned u; float f; } v; v.u = u & 0xffff0000u; return v.f;
}
__device__ __forceinline__ float4 shfl_xor4(float4 v, int m) {
    v.x = __shfl_xor(v.x, m); v.y = __shfl_xor(v.y, m);
    v.z = __shfl_xor(v.z, m); v.w = __shfl_xor(v.w, m);
    return v;
}

// async global->LDS, 16B per lane; LDS dest = wave-uniform base + lane*16
__device__ __forceinline__ void async_load16(const void* g, void* l) {
    __builtin_amdgcn_global_load_lds(
        (const __attribute__((address_space(1))) unsigned int*)g,
        (__attribute__((address_space(3))) unsigned int*)l, 16, 0, 0);
}

// all-256-thread block reduce of two values (sum, sumsq)
__device__ __forceinline__ void block_reduce2(float v1, float v2, float* red1, float* red2,
                                              int tid, float& o1, float& o2) {
    red1[tid] = v1; red2[tid] = v2;
    __syncthreads();
    for (int s = 128; s > 0; s >>= 1) {
        if (tid < s) { red1[tid] += red1[tid + s]; red2[tid] += red2[tid + s]; }
        __syncthreads();
    }
    o1 = red1[0]; o2 = red2[0];
    __syncthreads();
}

// ---------------- weight convert: Wtb[d][c] = bf16( (d<256?Wk:Wv)[d%256][c] ) ----------------
__global__ void wtb_kernel(const float* __restrict__ Wk, const float* __restrict__ Wv,
                           unsigned short* __restrict__ Wtb) {
    int t = blockIdx.x * 256 + threadIdx.x;   // 0..131071
    int d = t >> 8;
    int c = t & 255;
    float v = (d < 256) ? Wk[d * 256 + c] : Wv[(d - 256) * 256 + c];
    Wtb[t] = f2bf(v);
}

// ---------------- LN stats per (b,n) row over c ----------------
__global__ void ln_stats_kernel(const float* __restrict__ x, float* __restrict__ mean,
                                float* __restrict__ rstd) {
    int t = blockIdx.x * 256 + threadIdx.x;   // 0..65535
    int b = t >> 12;
    int n = t & 4095;
    const float* xb = x + (size_t)b * C_ * NPIX + n;
    float s = 0.f, s2 = 0.f;
    #pragma unroll 8
    for (int c = 0; c < C_; ++c) {
        float v = xb[(size_t)c * NPIX];
        s += v; s2 += v * v;
    }
    float m = s * (1.0f / C_);
    float var = s2 * (1.0f / C_) - m * m;
    mean[t] = m;
    rstd[t] = rsqrtf(var + 1e-5f);
}

// ---------------- slots init ----------------
__global__ void init_slots_kernel(const float* __restrict__ noise, const float* __restrict__ mu,
                                  const float* __restrict__ log_sigma, float* __restrict__ slots) {
    int t = blockIdx.x * 256 + threadIdx.x;   // 0..16383
    int c = t & 255;
    slots[t] = mu[c] + expf(log_sigma[c]) * noise[t];
}

// ---------------- LN + transpose + bf16 convert: xnb[b*4096+n][c] ----------------
__global__ __launch_bounds__(256) void xn_bf16_kernel(
    const float* __restrict__ x, const float* __restrict__ mean, const float* __restrict__ rstd,
    const float* __restrict__ g, const float* __restrict__ bta,
    unsigned short* __restrict__ xnb) {
    __shared__ float tile[64][65];
    int tid = threadIdx.x;
    int nt = blockIdx.x << 6, ct = blockIdx.y << 6, b = blockIdx.z;
    #pragma unroll
    for (int r = 0; r < 16; ++r) {
        int idx = tid + (r << 8);
        int c_l = idx >> 6, n_l = idx & 63;
        tile[c_l][n_l] = x[(size_t)(b * C_ + ct + c_l) * NPIX + nt + n_l];
    }
    __syncthreads();
    #pragma unroll
    for (int r = 0; r < 8; ++r) {
        int idx = tid + (r << 8);         // 0..2047
        int n_l = idx >> 5, cp = idx & 31;
        int c0 = cp << 1;
        int gn = b * NPIX + nt + n_l;
        float mn = mean[gn], rs = rstd[gn];
        float v0 = (tile[c0][n_l] - mn) * rs * g[ct + c0] + bta[ct + c0];
        float v1 = (tile[c0 + 1][n_l] - mn) * rs * g[ct + c0 + 1] + bta[ct + c0 + 1];
        ushort2 o; o.x = f2bf(v0); o.y = f2bf(v1);
        *reinterpret_cast<ushort2*>(&xnb[(size_t)gn * C_ + ct + c0]) = o;
    }
}

// ---------------- bf16 MFMA k/v projection GEMM (m97 structure) ----------------
__global__ __launch_bounds__(256) void kv_gemm_mfma(
    const unsigned short* __restrict__ xnb, const unsigned short* __restrict__ Wtb,
    const float* __restrict__ bk, const float* __restrict__ bv,
    unsigned short* __restrict__ kbuf, unsigned short* __restrict__ vbuf) {
    __shared__ __align__(16) short As[128 * 32];
    __shared__ __align__(16) short Bs[128 * 32];
    const int tid = threadIdx.x;
    const int wave = tid >> 6, lane = tid & 63;
    const int mtile = blockIdx.x << 7;
    const int ntile = blockIdx.y << 7;
    const int wr = wave >> 1, wc = wave & 1;

    f32x4 acc[4][4];
    #pragma unroll
    for (int i = 0; i < 4; ++i)
        #pragma unroll
        for (int j = 0; j < 4; ++j) acc[i][j] = (f32x4)0.f;

    const int lrow = lane >> 2;
    const int lk   = (lane & 3) << 3;

    for (int kc0 = 0; kc0 < C_; kc0 += 32) {
        #pragma unroll
        for (int j = 0; j < 2; ++j) {
            int row = (wave << 5) + (j << 4) + lrow;
            async_load16(&xnb[(size_t)(mtile + row) * C_ + kc0 + lk],
                         &As[(wave << 10) + (j << 9)]);
            async_load16(&Wtb[(size_t)(ntile + row) * C_ + kc0 + lk],
                         &Bs[(wave << 10) + (j << 9)]);
        }
        __syncthreads();
        bf16x8 af[4], bfr[4];
        #pragma unroll
        for (int mi = 0; mi < 4; ++mi)
            af[mi] = *reinterpret_cast<const bf16x8*>(
                &As[((wr << 6) + (mi << 4) + (lane & 15)) * 32 + ((lane >> 4) << 3)]);
        #pragma unroll
        for (int ni = 0; ni < 4; ++ni)
            bfr[ni] = *reinterpret_cast<const bf16x8*>(
                &Bs[((wc << 6) + (ni << 4) + (lane & 15)) * 32 + ((lane >> 4) << 3)]);
        #pragma unroll
        for (int mi = 0; mi < 4; ++mi)
            #pragma unroll
            for (int ni = 0; ni < 4; ++ni)
                acc[mi][ni] = __builtin_amdgcn_mfma_f32_16x16x32_bf16(
                    af[mi], bfr[ni], acc[mi][ni], 0, 0, 0);
        __syncthreads();
    }

    #pragma unroll
    for (int ni = 0; ni < 4; ++ni) {
        int col = ntile + (wc << 6) + (ni << 4) + (lane & 15);
        bool is_k = (col < 256);
        float bias = is_k ? bk[col] : bv[col - 256];
        unsigned short* obuf = is_k ? kbuf : vbuf;
        int cl = is_k ? col : (col - 256);
        #pragma unroll
        for (int mi = 0; mi < 4; ++mi) {
            int row0 = mtile + (wr << 6) + (mi << 4) + ((lane >> 4) << 2);
            #pragma unroll
            for (int r = 0; r < 4; ++r)
                obuf[(size_t)(row0 + r) * C_ + cl] = f2bf(acc[mi][ni][r] + bias);
        }
    }
}

// ---------------- slot LN + q projection ----------------
__global__ __launch_bounds__(256) void slot_q_kernel(
    const float* __restrict__ slots, const float* __restrict__ g_sl, const float* __restrict__ b_sl,
    const float* __restrict__ Wq, const float* __restrict__ bq,
    float* __restrict__ qbuf) {
    __shared__ float snorm[256];
    __shared__ float red1[256], red2[256];
    int tid = threadIdx.x;
    int r = blockIdx.x;                 // b*K + k
    float v = slots[r * C_ + tid];
    float sm, s2;
    block_reduce2(v, v * v, red1, red2, tid, sm, s2);
    float m = sm * (1.f / C_);
    float rs = rsqrtf(s2 * (1.f / C_) - m * m + 1e-5f);
    snorm[tid] = (v - m) * rs * g_sl[tid] + b_sl[tid];
    __syncthreads();
    float qv = bq[tid];
    const float* wr = Wq + (size_t)tid * C_;
    #pragma unroll 8
    for (int c = 0; c < C_; ++c) qv += wr[c] * snorm[c];
    qbuf[r * C_ + tid] = qv;
}

// ---------------- fused attention: logits + softmax-over-K + weighted-v partials ----------------
// grid (64 n-chunks, 16 b), 256 threads. Deterministic: writes partials[b][chunk][k][c] + asump.
__global__ __launch_bounds__(256) void attn_fused_kernel(
    const float* __restrict__ qbuf, const unsigned short* __restrict__ kbuf,
    const unsigned short* __restrict__ vbuf,
    float* __restrict__ partials, float* __restrict__ asump) {
    __shared__ float4 qT[264];          // qT[c + (c>>5)] = (q0,q1,q2,q3)[c], padded
    __shared__ float attns[K_][64];
    __shared__ float upd_s[K_][256];
    __shared__ float asw[4][4];         // [wave][k]

    const int tid = threadIdx.x;
    const int b = blockIdx.y;
    const int chunk = blockIdx.x;       // 0..63
    const int n0 = chunk << 6;
    const int wave = tid >> 6, lane = tid & 63;

    // ---- stage qT (k-major float4 per c) ----
    {
        int c = tid;
        float4 qv;
        qv.x = qbuf[b * 1024 + c];
        qv.y = qbuf[b * 1024 + 256 + c];
        qv.z = qbuf[b * 1024 + 512 + c];
        qv.w = qbuf[b * 1024 + 768 + c];
        qT[c + (c >> 5)] = qv;
    }
    __syncthreads();

    // ---- phase A: logits for 64 n, softmax over K ----
    const int cpart = tid & 7;          // 8 c-parts of 32 c
    const int npair = tid >> 3;         // 0..31 (2 n each)
    const int c0 = cpart << 5;
    float4 acc0 = {0.f, 0.f, 0.f, 0.f}, acc1 = {0.f, 0.f, 0.f, 0.f};
    const unsigned short* kbase = kbuf + ((size_t)b * NPIX + n0 + npair * 2) * C_ + c0;
    #pragma unroll
    for (int j = 0; j < 4; ++j) {       // 4 x 16B per row = 32 c
        uint4 k0 = *reinterpret_cast<const uint4*>(kbase + j * 8);
        uint4 k1 = *reinterpret_cast<const uint4*>(kbase + C_ + j * 8);
        const unsigned kw0[4] = {k0.x, k0.y, k0.z, k0.w};
        const unsigned kw1[4] = {k1.x, k1.y, k1.z, k1.w};
        #pragma unroll
        for (int jj = 0; jj < 4; ++jj) {
            int cidx = c0 + j * 8 + jj * 2 + cpart;   // padded index
            float4 qa = qT[cidx];
            float4 qb = qT[cidx + 1];
            float f00 = bflo(kw0[jj]), f01 = bfhi(kw0[jj]);
            float f10 = bflo(kw1[jj]), f11 = bfhi(kw1[jj]);
            acc0.x += f00 * qa.x + f01 * qb.x;  acc0.y += f00 * qa.y + f01 * qb.y;
            acc0.z += f00 * qa.z + f01 * qb.z;  acc0.w += f00 * qa.w + f01 * qb.w;
            acc1.x += f10 * qa.x + f11 * qb.x;  acc1.y += f10 * qa.y + f11 * qb.y;
            acc1.z += f10 * qa.z + f11 * qb.z;  acc1.w += f10 * qa.w + f11 * qb.w;
        }
    }
    // butterfly over the 8 c-parts (lane bits 0..2)
    #pragma unroll
    for (int m = 1; m <= 4; m <<= 1) {
        acc0 = acc0 + shfl_xor4(acc0, m);
        acc1 = acc1 + shfl_xor4(acc1, m);
    }
    // softmax over K (scale 1/16)
    float4 w0, w1;
    {
        float4 l = acc0 * 0.0625f;
        float mx = fmaxf(fmaxf(l.x, l.y), fmaxf(l.z, l.w));
        w0.x = expf(l.x - mx); w0.y = expf(l.y - mx);
        w0.z = expf(l.z - mx); w0.w = expf(l.w - mx);
        float inv = 1.0f / (w0.x + w0.y + w0.z + w0.w);
        w0 = w0 * inv;
        l = acc1 * 0.0625f;
        mx = fmaxf(fmaxf(l.x, l.y), fmaxf(l.z, l.w));
        w1.x = expf(l.x - mx); w1.y = expf(l.y - mx);
        w1.z = expf(l.z - mx); w1.w = expf(l.w - mx);
        inv = 1.0f / (w1.x + w1.y + w1.z + w1.w);
        w1 = w1 * inv;
    }
    if (cpart == 0) {
        int n_l = npair * 2;
        attns[0][n_l] = w0.x; attns[1][n_l] = w0.y; attns[2][n_l] = w0.z; attns[3][n_l] = w0.w;
        attns[0][n_l + 1] = w1.x; attns[1][n_l + 1] = w1.y;
        attns[2][n_l + 1] = w1.z; attns[3][n_l + 1] = w1.w;
    }
    // asum partial: butterfly over npair bits within wave (lane bits 3..5)
    float4 ws = w0 + w1;
    #pragma unroll
    for (int m = 8; m <= 32; m <<= 1) ws = ws + shfl_xor4(ws, m);
    if (lane == 0) {
        asw[wave][0] = ws.x; asw[wave][1] = ws.y; asw[wave][2] = ws.z; asw[wave][3] = ws.w;
    }
    __syncthreads();
    if (tid < 4)
        asump[(b * 64 + chunk) * 4 + tid] =
            asw[0][tid] + asw[1][tid] + asw[2][tid] + asw[3][tid];

    // ---- phase B: upd partial = sum_n w[k,n] * v[n,c] ----
    const int h = wave >> 1;            // n-half
    const int chalf = (wave & 1) << 7;  // c-half base
    const int c = chalf + lane * 2;
    float a0[K_] = {0.f, 0.f, 0.f, 0.f};  // c
    float a1[K_] = {0.f, 0.f, 0.f, 0.f};  // c+1
    const unsigned short* vbase = vbuf + ((size_t)b * NPIX + n0 + h * 32) * C_ + c;
    #pragma unroll 4
    for (int nn = 0; nn < 32; ++nn) {
        unsigned vv = *reinterpret_cast<const unsigned*>(vbase + (size_t)nn * C_);
        float v0 = bflo(vv), v1 = bfhi(vv);
        int n_l = h * 32 + nn;
        float q0 = attns[0][n_l], q1 = attns[1][n_l], q2 = attns[2][n_l], q3 = attns[3][n_l];
        a0[0] = fmaf(q0, v0, a0[0]); a1[0] = fmaf(q0, v1, a1[0]);
        a0[1] = fmaf(q1, v0, a0[1]); a1[1] = fmaf(q1, v1, a1[1]);
        a0[2] = fmaf(q2, v0, a0[2]); a1[2] = fmaf(q2, v1, a1[2]);
        a0[3] = fmaf(q3, v0, a0[3]); a1[3] = fmaf(q3, v1, a1[3]);
    }
    __syncthreads();
    if (h == 0) {
        #pragma unroll
        for (int k = 0; k < K_; ++k) {
            upd_s[k][c] = a0[k]; upd_s[k][c + 1] = a1[k];
        }
    }
    __syncthreads();
    if (h == 1) {
        #pragma unroll
        for (int k = 0; k < K_; ++k) {
            upd_s[k][c] += a0[k]; upd_s[k][c + 1] += a1[k];
        }
    }
    __syncthreads();
    float* pb = partials + (size_t)(b * 64 + chunk) * (K_ * 256);
    #pragma unroll
    for (int k = 0; k < K_; ++k) pb[k * 256 + tid] = upd_s[k][tid];
}

// ---------------- slot update: reduce partials, Wu GEMM + residual + LN + MLP ----------------
__global__ __launch_bounds__(256) void slot_update_kernel(
    float* __restrict__ slots, const float* __restrict__ partials, const float* __restrict__ asump,
    const float* __restrict__ Wu, const float* __restrict__ bu,
    const float* __restrict__ g_mlp, const float* __restrict__ b_mlp,
    const float* __restrict__ W1, const float* __restrict__ b1,
    const float* __restrict__ W2, const float* __restrict__ b2) {
    __shared__ float comb[512];
    __shared__ float mrow[256];
    __shared__ float hrow[512];
    __shared__ float red1[256], red2[256];
    int tid = threadIdx.x;
    int r = blockIdx.x;
    int b = r >> 2, kk = r & 3;
    float prev = slots[r * C_ + tid];
    comb[tid] = prev;
    // reduce upd partials (deterministic)
    float u = 0.f;
    #pragma unroll 8
    for (int j = 0; j < 64; ++j)
        u += partials[((size_t)(b * 64 + j) * 4 + kk) * 256 + tid];
    // reduce asum partials
    float dv = (tid < 64) ? asump[(b * 64 + tid) * 4 + kk] : 0.f;
    float sm_d, dummy;
    block_reduce2(dv, 0.f, red1, red2, tid, sm_d, dummy);
    float denom = sm_d + 1e-8f;
    comb[256 + tid] = u / denom;
    __syncthreads();
    float nv = bu[tid] + prev;
    const float* wrow = Wu + (size_t)tid * 512;
    #pragma unroll 8
    for (int c = 0; c < 512; ++c) nv = fmaf(wrow[c], comb[c], nv);
    float sm, s2;
    block_reduce2(nv, nv * nv, red1, red2, tid, sm, s2);
    float m = sm * (1.f / C_);
    float rs = rsqrtf(s2 * (1.f / C_) - m * m + 1e-5f);
    mrow[tid] = (nv - m) * rs * g_mlp[tid] + b_mlp[tid];
    __syncthreads();
    #pragma unroll
    for (int rep = 0; rep < 2; ++rep) {
        int j = tid + rep * 256;
        float hv = b1[j];
        const float* w1r = W1 + (size_t)j * C_;
        #pragma unroll 8
        for (int c = 0; c < C_; ++c) hv = fmaf(w1r[c], mrow[c], hv);
        hrow[j] = gelu_f(hv);
    }
    __syncthreads();
    float ov = nv + b2[tid];
    const float* w2r = W2 + (size_t)tid * 512;
    #pragma unroll 8
    for (int c = 0; c < 512; ++c) ov = fmaf(w2r[c], hrow[c], ov);
    slots[r * C_ + tid] = ov;
}

// ---------------- final head ----------------
__global__ __launch_bounds__(256) void final_kernel(
    const float* __restrict__ slots, const float* __restrict__ We1, const float* __restrict__ be1,
    const float* __restrict__ We2, const float* __restrict__ be2, float* __restrict__ out) {
    __shared__ float srow[256];
    __shared__ float erow[128];
    int tid = threadIdx.x;
    int r = blockIdx.x;
    float sv = slots[r * C_ + tid];
    srow[tid] = sv;
    out[r * C_ + tid] = sv;
    __syncthreads();
    if (tid < 128) {
        float ev = be1[tid];
        const float* wr = We1 + (size_t)tid * C_;
        #pragma unroll 8
        for (int c = 0; c < C_; ++c) ev = fmaf(wr[c], srow[c], ev);
        erow[tid] = gelu_f(ev);
    }
    __syncthreads();
    if (tid == 0) {
        float acc = be2[0];
        #pragma unroll 8
        for (int j = 0; j < 128; ++j) acc = fmaf(We2[j], erow[j], acc);
        out[B_ * K_ * C_ + r] = 1.0f / (1.0f + expf(-acc));
    }
}

extern "C" void kernel_launch(void* const* d_in, const int* in_sizes, int n_in,
                              void* d_out, int out_size, void* d_ws, size_t ws_size,
                              hipStream_t stream) {
    (void)in_sizes; (void)n_in; (void)out_size; (void)ws_size;
    const float* x        = (const float*)d_in[0];
    const float* noise    = (const float*)d_in[1];
    const float* slot_mu  = (const float*)d_in[2];
    const float* slot_ls  = (const float*)d_in[3];
    const float* ln_in_g  = (const float*)d_in[4];
    const float* ln_in_b  = (const float*)d_in[5];
    const float* ln_sl_g  = (const float*)d_in[6];
    const float* ln_sl_b  = (const float*)d_in[7];
    const float* ln_mlp_g = (const float*)d_in[8];
    const float* ln_mlp_b = (const float*)d_in[9];
    const float* Wq = (const float*)d_in[10];
    const float* bq = (const float*)d_in[11];
    const float* Wk = (const float*)d_in[12];
    const float* bk = (const float*)d_in[13];
    const float* Wv = (const float*)d_in[14];
    const float* bv = (const float*)d_in[15];
    const float* Wu = (const float*)d_in[16];
    const float* bu = (const float*)d_in[17];
    const float* W1 = (const float*)d_in[18];
    const float* b1 = (const float*)d_in[19];
    const float* W2 = (const float*)d_in[20];
    const float* b2 = (const float*)d_in[21];
    const float* We1 = (const float*)d_in[22];
    const float* be1 = (const float*)d_in[23];
    const float* We2 = (const float*)d_in[24];
    const float* be2 = (const float*)d_in[25];
    float* out = (float*)d_out;

    char* ws = (char*)d_ws;
    unsigned short* kbuf = (unsigned short*)ws;                 // 33.5 MB
    unsigned short* vbuf = kbuf + (size_t)NROWS * C_;           // 33.5 MB
    unsigned short* xnb  = vbuf + (size_t)NROWS * C_;           // 33.5 MB
    unsigned short* Wtb  = xnb + (size_t)NROWS * C_;            // 256 KB
    float* meanb = (float*)(Wtb + 512 * C_);
    float* rstdb = meanb + NROWS;
    float* slots = rstdb + NROWS;
    float* qbuf  = slots + B_ * K_ * C_;
    float* partials = qbuf + B_ * K_ * C_;                      // 16*64*4*256 = 16.8 MB
    float* asump = partials + (size_t)B_ * 64 * K_ * 256;       // 4096 floats

    wtb_kernel<<<512, 256, 0, stream>>>(Wk, Wv, Wtb);
    ln_stats_kernel<<<NROWS / 256, 256, 0, stream>>>(x, meanb, rstdb);
    init_slots_kernel<<<B_ * K_, 256, 0, stream>>>(noise, slot_mu, slot_ls, slots);
    xn_bf16_kernel<<<dim3(64, 4, 16), 256, 0, stream>>>(x, meanb, rstdb, ln_in_g, ln_in_b, xnb);
    kv_gemm_mfma<<<dim3(512, 4), 256, 0, stream>>>(xnb, Wtb, bk, bv, kbuf, vbuf);
    for (int it = 0; it < ITERS_; ++it) {
        slot_q_kernel<<<B_ * K_, 256, 0, stream>>>(slots, ln_sl_g, ln_sl_b, Wq, bq, qbuf);
        attn_fused_kernel<<<dim3(64, 16), 256, 0, stream>>>(qbuf, kbuf, vbuf, partials, asump);
        slot_update_kernel<<<B_ * K_, 256, 0, stream>>>(slots, partials, asump, Wu, bu,
                                                        ln_mlp_g, ln_mlp_b, W1, b1, W2, b2);
    }
    final_kernel<<<B_ * K_, 256, 0, stream>>>(slots, We1, be1, We2, be2, out);
}

// Round 4
// 371.324 us; speedup vs baseline: 2.4095x; 1.3127x over previous
//
#include <hip/hip_runtime.h>
#include <math.h>

#define B_    16
#define C_    256
#define NPIX  4096      // H*W
#define K_    4
#define HID_  512
#define ITERS_ 3
#define NROWS (B_*NPIX) // 65536

typedef __attribute__((ext_vector_type(8))) short bf16x8;
typedef __attribute__((ext_vector_type(4))) float f32x4;

__device__ __forceinline__ float gelu_f(float x) {
    return 0.5f * x * (1.0f + erff(x * 0.70710678118654752f));
}

__device__ __forceinline__ unsigned short f2bf(float x) {
    union { float f; unsigned u; } v; v.f = x;
    unsigned r = v.u + 0x7fffu + ((v.u >> 16) & 1u);   // round-nearest-even
    return (unsigned short)(r >> 16);
}
__device__ __forceinline__ float bflo(unsigned u) {
    union { unsigned u; float f; } v; v.u = u << 16; return v.f;
}
__device__ __forceinline__ float bfhi(unsigned u) {
    union { unsigned u; float f; } v; v.u = u & 0xffff0000u; return v.f;
}
__device__ __forceinline__ float4 shfl_xor4(float4 v, int m) {
    v.x = __shfl_xor(v.x, m); v.y = __shfl_xor(v.y, m);
    v.z = __shfl_xor(v.z, m); v.w = __shfl_xor(v.w, m);
    return v;
}

__device__ __forceinline__ void async_load16(const void* g, void* l) {
    __builtin_amdgcn_global_load_lds(
        (const __attribute__((address_space(1))) unsigned int*)g,
        (__attribute__((address_space(3))) unsigned int*)l, 16, 0, 0);
}

__device__ __forceinline__ void block_reduce2(float v1, float v2, float* red1, float* red2,
                                              int tid, float& o1, float& o2) {
    red1[tid] = v1; red2[tid] = v2;
    __syncthreads();
    for (int s = 128; s > 0; s >>= 1) {
        if (tid < s) { red1[tid] += red1[tid + s]; red2[tid] += red2[tid + s]; }
        __syncthreads();
    }
    o1 = red1[0]; o2 = red2[0];
    __syncthreads();
}

// ---------------- prep: bf16 kv weights + transposed fp32 slot weights ----------------
// segments: Wtb[d][c] (131072) | WqT[c][d] (65536) | WuT[c][d] (131072, c<512)
//         | W1T[c][h] (131072) | W2T[h][d] (131072) | We1T[c][e] (32768)
__global__ void prep_kernel(const float* __restrict__ Wk, const float* __restrict__ Wv,
                            const float* __restrict__ Wq, const float* __restrict__ Wu,
                            const float* __restrict__ W1, const float* __restrict__ W2,
                            const float* __restrict__ We1,
                            unsigned short* __restrict__ Wtb, float* __restrict__ WqT,
                            float* __restrict__ WuT, float* __restrict__ W1T,
                            float* __restrict__ W2T, float* __restrict__ We1T) {
    int t = blockIdx.x * 256 + threadIdx.x;
    if (t < 131072) {
        int d = t >> 8, c = t & 255;
        float v = (d < 256) ? Wk[d * 256 + c] : Wv[(d - 256) * 256 + c];
        Wtb[t] = f2bf(v);
    } else if (t < 196608) {
        int i = t - 131072; int c = i >> 8, d = i & 255;
        WqT[i] = Wq[d * 256 + c];
    } else if (t < 327680) {
        int i = t - 196608; int c = i >> 8, d = i & 255;
        WuT[i] = Wu[d * 512 + c];
    } else if (t < 458752) {
        int i = t - 327680; int c = i >> 9, h = i & 511;
        W1T[i] = W1[h * 256 + c];
    } else if (t < 589824) {
        int i = t - 458752; int h = i >> 8, d = i & 255;
        W2T[i] = W2[d * 512 + h];
    } else if (t < 622592) {
        int i = t - 589824; int c = i >> 7, e = i & 127;
        We1T[i] = We1[e * 256 + c];
    }
}

// ---------------- fused LN(+stats) + transpose + bf16 convert, single x pass ----------------
// grid (64 n-tiles, 16 b), 256 threads; block covers 64 n x all 256 c
__global__ __launch_bounds__(256) void xn_fused_kernel(
    const float* __restrict__ x, const float* __restrict__ g, const float* __restrict__ bta,
    unsigned short* __restrict__ xnb) {
    __shared__ float tile[256][65];
    __shared__ float sg[256], sb[256];
    __shared__ float red1[256], red2[256];
    __shared__ float smean[64], srstd[64];
    const int tid = threadIdx.x;
    const int nt = blockIdx.x << 6, b = blockIdx.y;

    sg[tid] = g[tid]; sb[tid] = bta[tid];
    #pragma unroll
    for (int r = 0; r < 64; ++r) {
        int idx = tid + (r << 8);
        int c_l = idx >> 6, n_l = idx & 63;
        tile[c_l][n_l] = x[(size_t)(b * C_ + c_l) * NPIX + nt + n_l];
    }
    __syncthreads();
    // stats: thread (cq, n_l) partial over 64 c
    {
        int cq = tid >> 6, n_l = tid & 63;
        float s = 0.f, s2 = 0.f;
        #pragma unroll 8
        for (int c = cq * 64; c < cq * 64 + 64; ++c) {
            float v = tile[c][n_l];
            s += v; s2 += v * v;
        }
        red1[tid] = s; red2[tid] = s2;
    }
    __syncthreads();
    if (tid < 64) {
        float s  = red1[tid] + red1[tid + 64] + red1[tid + 128] + red1[tid + 192];
        float s2 = red2[tid] + red2[tid + 64] + red2[tid + 128] + red2[tid + 192];
        float m = s * (1.0f / C_);
        smean[tid] = m;
        srstd[tid] = rsqrtf(s2 * (1.0f / C_) - m * m + 1e-5f);
    }
    __syncthreads();
    #pragma unroll
    for (int r = 0; r < 32; ++r) {
        int idx = tid + (r << 8);          // 0..8191
        int n_l = idx >> 7, cp = idx & 127;
        int c0 = cp << 1;
        float mn = smean[n_l], rs = srstd[n_l];
        float v0 = (tile[c0][n_l] - mn) * rs * sg[c0] + sb[c0];
        float v1 = (tile[c0 + 1][n_l] - mn) * rs * sg[c0 + 1] + sb[c0 + 1];
        ushort2 o; o.x = f2bf(v0); o.y = f2bf(v1);
        *reinterpret_cast<ushort2*>(&xnb[((size_t)(b * NPIX + nt + n_l)) * C_ + c0]) = o;
    }
}

// ---------------- bf16 MFMA k/v projection GEMM (m97 structure) ----------------
__global__ __launch_bounds__(256) void kv_gemm_mfma(
    const unsigned short* __restrict__ xnb, const unsigned short* __restrict__ Wtb,
    const float* __restrict__ bk, const float* __restrict__ bv,
    unsigned short* __restrict__ kbuf, unsigned short* __restrict__ vbuf) {
    __shared__ __align__(16) short As[128 * 32];
    __shared__ __align__(16) short Bs[128 * 32];
    const int tid = threadIdx.x;
    const int wave = tid >> 6, lane = tid & 63;
    const int mtile = blockIdx.x << 7;
    const int ntile = blockIdx.y << 7;
    const int wr = wave >> 1, wc = wave & 1;

    f32x4 acc[4][4];
    #pragma unroll
    for (int i = 0; i < 4; ++i)
        #pragma unroll
        for (int j = 0; j < 4; ++j) acc[i][j] = (f32x4)0.f;

    const int lrow = lane >> 2;
    const int lk   = (lane & 3) << 3;

    for (int kc0 = 0; kc0 < C_; kc0 += 32) {
        #pragma unroll
        for (int j = 0; j < 2; ++j) {
            int row = (wave << 5) + (j << 4) + lrow;
            async_load16(&xnb[(size_t)(mtile + row) * C_ + kc0 + lk],
                         &As[(wave << 10) + (j << 9)]);
            async_load16(&Wtb[(size_t)(ntile + row) * C_ + kc0 + lk],
                         &Bs[(wave << 10) + (j << 9)]);
        }
        __syncthreads();
        bf16x8 af[4], bfr[4];
        #pragma unroll
        for (int mi = 0; mi < 4; ++mi)
            af[mi] = *reinterpret_cast<const bf16x8*>(
                &As[((wr << 6) + (mi << 4) + (lane & 15)) * 32 + ((lane >> 4) << 3)]);
        #pragma unroll
        for (int ni = 0; ni < 4; ++ni)
            bfr[ni] = *reinterpret_cast<const bf16x8*>(
                &Bs[((wc << 6) + (ni << 4) + (lane & 15)) * 32 + ((lane >> 4) << 3)]);
        #pragma unroll
        for (int mi = 0; mi < 4; ++mi)
            #pragma unroll
            for (int ni = 0; ni < 4; ++ni)
                acc[mi][ni] = __builtin_amdgcn_mfma_f32_16x16x32_bf16(
                    af[mi], bfr[ni], acc[mi][ni], 0, 0, 0);
        __syncthreads();
    }

    #pragma unroll
    for (int ni = 0; ni < 4; ++ni) {
        int col = ntile + (wc << 6) + (ni << 4) + (lane & 15);
        bool is_k = (col < 256);
        float bias = is_k ? bk[col] : bv[col - 256];
        unsigned short* obuf = is_k ? kbuf : vbuf;
        int cl = is_k ? col : (col - 256);
        #pragma unroll
        for (int mi = 0; mi < 4; ++mi) {
            int row0 = mtile + (wr << 6) + (mi << 4) + ((lane >> 4) << 2);
            #pragma unroll
            for (int r = 0; r < 4; ++r)
                obuf[(size_t)(row0 + r) * C_ + cl] = f2bf(acc[mi][ni][r] + bias);
        }
    }
}

// ---------------- shared device code: LN(slots row) + q projection, coalesced WqT ----------------
__device__ __forceinline__ void ln_q_body(float v, int tid, int r,
                                          const float* __restrict__ g_sl,
                                          const float* __restrict__ b_sl,
                                          const float* __restrict__ WqT,
                                          const float* __restrict__ bq,
                                          float* __restrict__ qbuf,
                                          float* snorm, float* red1, float* red2) {
    float sm, s2;
    block_reduce2(v, v * v, red1, red2, tid, sm, s2);
    float m = sm * (1.f / C_);
    float rs = rsqrtf(s2 * (1.f / C_) - m * m + 1e-5f);
    snorm[tid] = (v - m) * rs * g_sl[tid] + b_sl[tid];
    __syncthreads();
    float q0 = 0.f, q1 = 0.f, q2 = 0.f, q3 = 0.f;
    #pragma unroll 8
    for (int c = 0; c < C_; c += 4) {
        q0 = fmaf(WqT[(c + 0) * C_ + tid], snorm[c + 0], q0);
        q1 = fmaf(WqT[(c + 1) * C_ + tid], snorm[c + 1], q1);
        q2 = fmaf(WqT[(c + 2) * C_ + tid], snorm[c + 2], q2);
        q3 = fmaf(WqT[(c + 3) * C_ + tid], snorm[c + 3], q3);
    }
    qbuf[r * C_ + tid] = (q0 + q1) + (q2 + q3) + bq[tid];
}

// ---------------- fused slots init + q0 ----------------
__global__ __launch_bounds__(256) void slot_init_q_kernel(
    const float* __restrict__ noise, const float* __restrict__ mu,
    const float* __restrict__ log_sigma,
    const float* __restrict__ g_sl, const float* __restrict__ b_sl,
    const float* __restrict__ WqT, const float* __restrict__ bq,
    float* __restrict__ slots, float* __restrict__ qbuf) {
    __shared__ float snorm[256];
    __shared__ float red1[256], red2[256];
    int tid = threadIdx.x;
    int r = blockIdx.x;
    float v = mu[tid] + expf(log_sigma[tid]) * noise[r * C_ + tid];
    slots[r * C_ + tid] = v;
    ln_q_body(v, tid, r, g_sl, b_sl, WqT, bq, qbuf, snorm, red1, red2);
}

// ---------------- fused attention (unchanged structure) ----------------
__global__ __launch_bounds__(256) void attn_fused_kernel(
    const float* __restrict__ qbuf, const unsigned short* __restrict__ kbuf,
    const unsigned short* __restrict__ vbuf,
    float* __restrict__ partials, float* __restrict__ asump) {
    __shared__ float4 qT[264];
    __shared__ float attns[K_][64];
    __shared__ float upd_s[K_][256];
    __shared__ float asw[4][4];

    const int tid = threadIdx.x;
    const int b = blockIdx.y;
    const int chunk = blockIdx.x;
    const int n0 = chunk << 6;
    const int wave = tid >> 6, lane = tid & 63;

    {
        int c = tid;
        float4 qv;
        qv.x = qbuf[b * 1024 + c];
        qv.y = qbuf[b * 1024 + 256 + c];
        qv.z = qbuf[b * 1024 + 512 + c];
        qv.w = qbuf[b * 1024 + 768 + c];
        qT[c + (c >> 5)] = qv;
    }
    __syncthreads();

    const int cpart = tid & 7;
    const int npair = tid >> 3;
    const int c0 = cpart << 5;
    float4 acc0 = {0.f, 0.f, 0.f, 0.f}, acc1 = {0.f, 0.f, 0.f, 0.f};
    const unsigned short* kbase = kbuf + ((size_t)b * NPIX + n0 + npair * 2) * C_ + c0;
    #pragma unroll
    for (int j = 0; j < 4; ++j) {
        uint4 k0 = *reinterpret_cast<const uint4*>(kbase + j * 8);
        uint4 k1 = *reinterpret_cast<const uint4*>(kbase + C_ + j * 8);
        const unsigned kw0[4] = {k0.x, k0.y, k0.z, k0.w};
        const unsigned kw1[4] = {k1.x, k1.y, k1.z, k1.w};
        #pragma unroll
        for (int jj = 0; jj < 4; ++jj) {
            int cidx = c0 + j * 8 + jj * 2 + cpart;
            float4 qa = qT[cidx];
            float4 qb = qT[cidx + 1];
            float f00 = bflo(kw0[jj]), f01 = bfhi(kw0[jj]);
            float f10 = bflo(kw1[jj]), f11 = bfhi(kw1[jj]);
            acc0.x += f00 * qa.x + f01 * qb.x;  acc0.y += f00 * qa.y + f01 * qb.y;
            acc0.z += f00 * qa.z + f01 * qb.z;  acc0.w += f00 * qa.w + f01 * qb.w;
            acc1.x += f10 * qa.x + f11 * qb.x;  acc1.y += f10 * qa.y + f11 * qb.y;
            acc1.z += f10 * qa.z + f11 * qb.z;  acc1.w += f10 * qa.w + f11 * qb.w;
        }
    }
    #pragma unroll
    for (int m = 1; m <= 4; m <<= 1) {
        acc0 = acc0 + shfl_xor4(acc0, m);
        acc1 = acc1 + shfl_xor4(acc1, m);
    }
    float4 w0, w1;
    {
        float4 l = acc0 * 0.0625f;
        float mx = fmaxf(fmaxf(l.x, l.y), fmaxf(l.z, l.w));
        w0.x = expf(l.x - mx); w0.y = expf(l.y - mx);
        w0.z = expf(l.z - mx); w0.w = expf(l.w - mx);
        float inv = 1.0f / (w0.x + w0.y + w0.z + w0.w);
        w0 = w0 * inv;
        l = acc1 * 0.0625f;
        mx = fmaxf(fmaxf(l.x, l.y), fmaxf(l.z, l.w));
        w1.x = expf(l.x - mx); w1.y = expf(l.y - mx);
        w1.z = expf(l.z - mx); w1.w = expf(l.w - mx);
        inv = 1.0f / (w1.x + w1.y + w1.z + w1.w);
        w1 = w1 * inv;
    }
    if (cpart == 0) {
        int n_l = npair * 2;
        attns[0][n_l] = w0.x; attns[1][n_l] = w0.y; attns[2][n_l] = w0.z; attns[3][n_l] = w0.w;
        attns[0][n_l + 1] = w1.x; attns[1][n_l + 1] = w1.y;
        attns[2][n_l + 1] = w1.z; attns[3][n_l + 1] = w1.w;
    }
    float4 ws = w0 + w1;
    #pragma unroll
    for (int m = 8; m <= 32; m <<= 1) ws = ws + shfl_xor4(ws, m);
    if (lane == 0) {
        asw[wave][0] = ws.x; asw[wave][1] = ws.y; asw[wave][2] = ws.z; asw[wave][3] = ws.w;
    }
    __syncthreads();
    if (tid < 4)
        asump[(b * 64 + chunk) * 4 + tid] =
            asw[0][tid] + asw[1][tid] + asw[2][tid] + asw[3][tid];

    const int h = wave >> 1;
    const int chalf = (wave & 1) << 7;
    const int c = chalf + lane * 2;
    float a0[K_] = {0.f, 0.f, 0.f, 0.f};
    float a1[K_] = {0.f, 0.f, 0.f, 0.f};
    const unsigned short* vbase = vbuf + ((size_t)b * NPIX + n0 + h * 32) * C_ + c;
    #pragma unroll 4
    for (int nn = 0; nn < 32; ++nn) {
        unsigned vv = *reinterpret_cast<const unsigned*>(vbase + (size_t)nn * C_);
        float v0 = bflo(vv), v1 = bfhi(vv);
        int n_l = h * 32 + nn;
        float q0 = attns[0][n_l], q1 = attns[1][n_l], q2 = attns[2][n_l], q3 = attns[3][n_l];
        a0[0] = fmaf(q0, v0, a0[0]); a1[0] = fmaf(q0, v1, a1[0]);
        a0[1] = fmaf(q1, v0, a0[1]); a1[1] = fmaf(q1, v1, a1[1]);
        a0[2] = fmaf(q2, v0, a0[2]); a1[2] = fmaf(q2, v1, a1[2]);
        a0[3] = fmaf(q3, v0, a0[3]); a1[3] = fmaf(q3, v1, a1[3]);
    }
    __syncthreads();
    if (h == 0) {
        #pragma unroll
        for (int k = 0; k < K_; ++k) { upd_s[k][c] = a0[k]; upd_s[k][c + 1] = a1[k]; }
    }
    __syncthreads();
    if (h == 1) {
        #pragma unroll
        for (int k = 0; k < K_; ++k) { upd_s[k][c] += a0[k]; upd_s[k][c + 1] += a1[k]; }
    }
    __syncthreads();
    float* pb = partials + (size_t)(b * 64 + chunk) * (K_ * 256);
    #pragma unroll
    for (int k = 0; k < K_; ++k) pb[k * 256 + tid] = upd_s[k][tid];
}

// ---------------- slot update core (transposed, coalesced weights) ----------------
__device__ __forceinline__ float slot_update_body(
    int tid, int r, const float* __restrict__ slots,
    const float* __restrict__ partials, const float* __restrict__ asump,
    const float* __restrict__ WuT, const float* __restrict__ bu,
    const float* __restrict__ g_mlp, const float* __restrict__ b_mlp,
    const float* __restrict__ W1T, const float* __restrict__ b1,
    const float* __restrict__ W2T, const float* __restrict__ b2,
    float* comb, float* mrow, float* hrow, float* red1, float* red2) {
    int b = r >> 2, kk = r & 3;
    float prev = slots[r * C_ + tid];
    comb[tid] = prev;
    float u0 = 0.f, u1 = 0.f;
    #pragma unroll 8
    for (int j = 0; j < 64; j += 2) {
        u0 += partials[((size_t)(b * 64 + j) * 4 + kk) * 256 + tid];
        u1 += partials[((size_t)(b * 64 + j + 1) * 4 + kk) * 256 + tid];
    }
    float dv = (tid < 64) ? asump[(b * 64 + tid) * 4 + kk] : 0.f;
    float sm_d, dummy;
    block_reduce2(dv, 0.f, red1, red2, tid, sm_d, dummy);
    comb[256 + tid] = (u0 + u1) / (sm_d + 1e-8f);
    __syncthreads();
    float n0 = 0.f, n1 = 0.f, n2 = 0.f, n3 = 0.f;
    #pragma unroll 8
    for (int c = 0; c < 512; c += 4) {
        n0 = fmaf(WuT[(c + 0) * C_ + tid], comb[c + 0], n0);
        n1 = fmaf(WuT[(c + 1) * C_ + tid], comb[c + 1], n1);
        n2 = fmaf(WuT[(c + 2) * C_ + tid], comb[c + 2], n2);
        n3 = fmaf(WuT[(c + 3) * C_ + tid], comb[c + 3], n3);
    }
    float nv = (n0 + n1) + (n2 + n3) + bu[tid] + prev;
    float sm, s2;
    block_reduce2(nv, nv * nv, red1, red2, tid, sm, s2);
    float m = sm * (1.f / C_);
    float rs = rsqrtf(s2 * (1.f / C_) - m * m + 1e-5f);
    mrow[tid] = (nv - m) * rs * g_mlp[tid] + b_mlp[tid];
    __syncthreads();
    #pragma unroll
    for (int rep = 0; rep < 2; ++rep) {
        int j = tid + rep * 256;
        float h0 = 0.f, h1 = 0.f, h2 = 0.f, h3 = 0.f;
        #pragma unroll 8
        for (int c = 0; c < C_; c += 4) {
            h0 = fmaf(W1T[(c + 0) * HID_ + j], mrow[c + 0], h0);
            h1 = fmaf(W1T[(c + 1) * HID_ + j], mrow[c + 1], h1);
            h2 = fmaf(W1T[(c + 2) * HID_ + j], mrow[c + 2], h2);
            h3 = fmaf(W1T[(c + 3) * HID_ + j], mrow[c + 3], h3);
        }
        hrow[j] = gelu_f((h0 + h1) + (h2 + h3) + b1[j]);
    }
    __syncthreads();
    float o0 = 0.f, o1 = 0.f, o2 = 0.f, o3 = 0.f;
    #pragma unroll 8
    for (int h = 0; h < 512; h += 4) {
        o0 = fmaf(W2T[(h + 0) * C_ + tid], hrow[h + 0], o0);
        o1 = fmaf(W2T[(h + 1) * C_ + tid], hrow[h + 1], o1);
        o2 = fmaf(W2T[(h + 2) * C_ + tid], hrow[h + 2], o2);
        o3 = fmaf(W2T[(h + 3) * C_ + tid], hrow[h + 3], o3);
    }
    return nv + (o0 + o1) + (o2 + o3) + b2[tid];
}

// ---------------- fused slot update + next-iteration q ----------------
__global__ __launch_bounds__(256) void slot_update_q_kernel(
    float* __restrict__ slots, const float* __restrict__ partials, const float* __restrict__ asump,
    const float* __restrict__ WuT, const float* __restrict__ bu,
    const float* __restrict__ g_mlp, const float* __restrict__ b_mlp,
    const float* __restrict__ W1T, const float* __restrict__ b1,
    const float* __restrict__ W2T, const float* __restrict__ b2,
    const float* __restrict__ g_sl, const float* __restrict__ b_sl,
    const float* __restrict__ WqT, const float* __restrict__ bq,
    float* __restrict__ qbuf) {
    __shared__ float comb[512];
    __shared__ float mrow[256];
    __shared__ float hrow[512];
    __shared__ float red1[256], red2[256];
    int tid = threadIdx.x;
    int r = blockIdx.x;
    float ov = slot_update_body(tid, r, slots, partials, asump, WuT, bu, g_mlp, b_mlp,
                                W1T, b1, W2T, b2, comb, mrow, hrow, red1, red2);
    slots[r * C_ + tid] = ov;
    __syncthreads();
    ln_q_body(ov, tid, r, g_sl, b_sl, WqT, bq, qbuf, mrow, red1, red2);
}

// ---------------- fused last slot update + final head ----------------
__global__ __launch_bounds__(256) void slot_update_final_kernel(
    float* __restrict__ slots, const float* __restrict__ partials, const float* __restrict__ asump,
    const float* __restrict__ WuT, const float* __restrict__ bu,
    const float* __restrict__ g_mlp, const float* __restrict__ b_mlp,
    const float* __restrict__ W1T, const float* __restrict__ b1,
    const float* __restrict__ W2T, const float* __restrict__ b2,
    const float* __restrict__ We1T, const float* __restrict__ be1,
    const float* __restrict__ We2, const float* __restrict__ be2,
    float* __restrict__ out) {
    __shared__ float comb[512];
    __shared__ float mrow[256];
    __shared__ float hrow[512];
    __shared__ float red1[256], red2[256];
    __shared__ float erow[128];
    int tid = threadIdx.x;
    int r = blockIdx.x;
    float ov = slot_update_body(tid, r, slots, partials, asump, WuT, bu, g_mlp, b_mlp,
                                W1T, b1, W2T, b2, comb, mrow, hrow, red1, red2);
    out[r * C_ + tid] = ov;
    mrow[tid] = ov;
    __syncthreads();
    if (tid < 128) {
        float e0 = 0.f, e1 = 0.f, e2 = 0.f, e3 = 0.f;
        #pragma unroll 8
        for (int c = 0; c < C_; c += 4) {
            e0 = fmaf(We1T[(c + 0) * 128 + tid], mrow[c + 0], e0);
            e1 = fmaf(We1T[(c + 1) * 128 + tid], mrow[c + 1], e1);
            e2 = fmaf(We1T[(c + 2) * 128 + tid], mrow[c + 2], e2);
            e3 = fmaf(We1T[(c + 3) * 128 + tid], mrow[c + 3], e3);
        }
        erow[tid] = gelu_f((e0 + e1) + (e2 + e3) + be1[tid]);
    }
    __syncthreads();
    if (tid == 0) {
        float acc = be2[0];
        #pragma unroll 8
        for (int j = 0; j < 128; ++j) acc = fmaf(We2[j], erow[j], acc);
        out[B_ * K_ * C_ + r] = 1.0f / (1.0f + expf(-acc));
    }
}

extern "C" void kernel_launch(void* const* d_in, const int* in_sizes, int n_in,
                              void* d_out, int out_size, void* d_ws, size_t ws_size,
                              hipStream_t stream) {
    (void)in_sizes; (void)n_in; (void)out_size; (void)ws_size;
    const float* x        = (const float*)d_in[0];
    const float* noise    = (const float*)d_in[1];
    const float* slot_mu  = (const float*)d_in[2];
    const float* slot_ls  = (const float*)d_in[3];
    const float* ln_in_g  = (const float*)d_in[4];
    const float* ln_in_b  = (const float*)d_in[5];
    const float* ln_sl_g  = (const float*)d_in[6];
    const float* ln_sl_b  = (const float*)d_in[7];
    const float* ln_mlp_g = (const float*)d_in[8];
    const float* ln_mlp_b = (const float*)d_in[9];
    const float* Wq = (const float*)d_in[10];
    const float* bq = (const float*)d_in[11];
    const float* Wk = (const float*)d_in[12];
    const float* bk = (const float*)d_in[13];
    const float* Wv = (const float*)d_in[14];
    const float* bv = (const float*)d_in[15];
    const float* Wu = (const float*)d_in[16];
    const float* bu = (const float*)d_in[17];
    const float* W1 = (const float*)d_in[18];
    const float* b1 = (const float*)d_in[19];
    const float* W2 = (const float*)d_in[20];
    const float* b2 = (const float*)d_in[21];
    const float* We1 = (const float*)d_in[22];
    const float* be1 = (const float*)d_in[23];
    const float* We2 = (const float*)d_in[24];
    const float* be2 = (const float*)d_in[25];
    float* out = (float*)d_out;

    char* ws = (char*)d_ws;
    unsigned short* kbuf = (unsigned short*)ws;
    unsigned short* vbuf = kbuf + (size_t)NROWS * C_;
    unsigned short* xnb  = vbuf + (size_t)NROWS * C_;
    unsigned short* Wtb  = xnb + (size_t)NROWS * C_;
    float* WqT  = (float*)(Wtb + 512 * C_);
    float* WuT  = WqT + 256 * 256;
    float* W1T  = WuT + 512 * 256;
    float* W2T  = W1T + 256 * 512;
    float* We1T = W2T + 512 * 256;
    float* slots = We1T + 256 * 128;
    float* qbuf  = slots + B_ * K_ * C_;
    float* partials = qbuf + B_ * K_ * C_;
    float* asump = partials + (size_t)B_ * 64 * K_ * 256;

    prep_kernel<<<2432, 256, 0, stream>>>(Wk, Wv, Wq, Wu, W1, W2, We1,
                                          Wtb, WqT, WuT, W1T, W2T, We1T);
    xn_fused_kernel<<<dim3(64, 16), 256, 0, stream>>>(x, ln_in_g, ln_in_b, xnb);
    slot_init_q_kernel<<<B_ * K_, 256, 0, stream>>>(noise, slot_mu, slot_ls,
                                                    ln_sl_g, ln_sl_b, WqT, bq, slots, qbuf);
    kv_gemm_mfma<<<dim3(512, 4), 256, 0, stream>>>(xnb, Wtb, bk, bv, kbuf, vbuf);
    for (int it = 0; it < ITERS_; ++it) {
        attn_fused_kernel<<<dim3(64, 16), 256, 0, stream>>>(qbuf, kbuf, vbuf, partials, asump);
        if (it < ITERS_ - 1) {
            slot_update_q_kernel<<<B_ * K_, 256, 0, stream>>>(
                slots, partials, asump, WuT, bu, ln_mlp_g, ln_mlp_b, W1T, b1, W2T, b2,
                ln_sl_g, ln_sl_b, WqT, bq, qbuf);
        } else {
            slot_update_final_kernel<<<B_ * K_, 256, 0, stream>>>(
                slots, partials, asump, WuT, bu, ln_mlp_g, ln_mlp_b, W1T, b1, W2T, b2,
                We1T, be1, We2, be2, out);
        }
    }
}